// Round 2
// baseline (854.048 us; speedup 1.0000x reference)
//
#include <hip/hip_runtime.h>
#include <hip/hip_bf16.h>
#include <stdint.h>

#define IN_F  2048
#define OUT_F 2048
#define BATCH 32768

typedef __attribute__((ext_vector_type(8))) short  short8;   // 8 x bf16 (4 VGPRs)
typedef __attribute__((ext_vector_type(4))) float  floatx4;  // MFMA C/D

// ---- old 128^2 pipeline constants (kept for k_gram_colsum) ----
static constexpr int LDT = 32;
static constexpr int TILE_USH = 128 * LDT;  // 4096 ushorts = 8 KB per tile

// ---- new 256x128 counted-vmcnt GEMM constants ----
#define BM 256
#define BN 128
#define BK 64
#define NKT (IN_F / BK)            // 32 K-tiles
#define A_TILE_USH (BM * BK)       // 16384 ush = 32 KB
#define B_TILE_USH (BN * BK)       // 8192 ush  = 16 KB

__device__ __forceinline__ uint16_t f2bf(float f) {
  union { float f; uint32_t u; } v; v.f = f;
  uint32_t r = v.u + 0x7FFFu + ((v.u >> 16) & 1u);  // RNE
  return (uint16_t)(r >> 16);
}

// 16B-wide async global->LDS. LDS dest is wave-uniform; HW scatters lane l at
// dest + l*16B. Global src is per-lane (enables source-side swizzle).
__device__ __forceinline__ void gl_lds16(const uint16_t* g, uint16_t* l) {
  __builtin_amdgcn_global_load_lds(
      (const __attribute__((address_space(1))) unsigned int*)(g),
      (__attribute__((address_space(3))) unsigned int*)(l), 16, 0, 0);
}

// ===================== old m97-structure pipeline (k_gram only) =====================
__device__ __forceinline__ void gemm128_pipeline(
    const uint16_t* __restrict__ A, const uint16_t* __restrict__ B,
    int bm, int bn, int K, uint16_t* sA, uint16_t* sB,
    floatx4 (&acc)[4][4]) {
  const int tid  = threadIdx.x;
  const int wave = tid >> 6, lane = tid & 63;
  const int wm = (wave >> 1) * 64, wn = (wave & 1) * 64;

  const int r0   = wave * 32 + (lane >> 2);
  const int scol = (lane & 3) * 8;
  const uint16_t* gA = A + (size_t)(bm + r0) * K + scol;
  const uint16_t* gB = B + (size_t)(bn + r0) * K + scol;
  const size_t rowK16 = (size_t)16 * K;

  const int ch0 = wave * 2 * (16 * LDT);
  const int ch1 = ch0 + 16 * LDT;

  const int ra = (wm + (lane & 15)) * LDT + (lane >> 4) * 8;
  const int rb = (wn + (lane & 15)) * LDT + (lane >> 4) * 8;

  gl_lds16(gA,          sA + ch0);
  gl_lds16(gA + rowK16, sA + ch1);
  gl_lds16(gB,          sB + ch0);
  gl_lds16(gB + rowK16, sB + ch1);
  gA += 32; gB += 32;
  __syncthreads();

  const int NK = K / 32;
  int p = 0;
  for (int k = 0; k < NK; k++, p ^= 1) {
    if (k + 1 < NK) {
      const int q = (p ^ 1) * TILE_USH;
      gl_lds16(gA,          sA + q + ch0);
      gl_lds16(gA + rowK16, sA + q + ch1);
      gl_lds16(gB,          sB + q + ch0);
      gl_lds16(gB + rowK16, sB + q + ch1);
      gA += 32; gB += 32;
    }
    const uint16_t* cA = sA + p * TILE_USH;
    const uint16_t* cB = sB + p * TILE_USH;
    short8 af[4], bf[4];
#pragma unroll
    for (int i = 0; i < 4; i++) {
      af[i] = *(const short8*)&cA[ra + i * 16 * LDT];
      bf[i] = *(const short8*)&cB[rb + i * 16 * LDT];
    }
#pragma unroll
    for (int i = 0; i < 4; i++)
#pragma unroll
      for (int j = 0; j < 4; j++)
        acc[i][j] = __builtin_amdgcn_mfma_f32_16x16x32_bf16(af[i], bf[j], acc[i][j], 0, 0, 0);
    __syncthreads();
  }
}

// ---------------- K1: P -> PT (bf16 transposed) and PB (bf16 straight) ----------------
__global__ __launch_bounds__(256) void k_prep(
    const float* __restrict__ P, uint16_t* __restrict__ PT,
    uint16_t* __restrict__ PB) {
  __shared__ float tile[32][33];
  const int bx = blockIdx.x * 32;  // i (IN)
  const int by = blockIdx.y * 32;  // k (OUT)
  const int tx = threadIdx.x & 31;
  const int ty = threadIdx.x >> 5;  // 0..7
#pragma unroll
  for (int i = 0; i < 32; i += 8) {
    float v = P[(size_t)(by + ty + i) * IN_F + bx + tx];
    tile[ty + i][tx] = v;
    PB[(size_t)(by + ty + i) * IN_F + bx + tx] = f2bf(v);
  }
  __syncthreads();
#pragma unroll
  for (int i = 0; i < 32; i += 8)
    PT[(size_t)(bx + ty + i) * IN_F + by + tx] = f2bf(tile[tx][ty + i]);
}

// ------- K2: colsum[j] += sum_i |sum_k PT[i,k] PT[j,k]| -------
__global__ __launch_bounds__(256) void k_gram_colsum(
    const uint16_t* __restrict__ PT, float* __restrict__ colsum) {
  __shared__ __align__(16) uint16_t sA[2 * TILE_USH];
  __shared__ __align__(16) uint16_t sB[2 * TILE_USH];
  __shared__ float colpart[128];

  const int tid = threadIdx.x;
  const int wave = tid >> 6, lane = tid & 63;
  const int bm = blockIdx.x * 128, bn = blockIdx.y * 128;
  const int wn = (wave & 1) * 64;

  floatx4 z = {0.f, 0.f, 0.f, 0.f};
  floatx4 acc[4][4];
#pragma unroll
  for (int i = 0; i < 4; i++)
#pragma unroll
    for (int j = 0; j < 4; j++) acc[i][j] = z;

  gemm128_pipeline(PT, PT, bm, bn, OUT_F, sA, sB, acc);

  if (tid < 128) colpart[tid] = 0.f;
  __syncthreads();
#pragma unroll
  for (int j = 0; j < 4; j++) {
    float s = 0.f;
#pragma unroll
    for (int i = 0; i < 4; i++)
#pragma unroll
      for (int r = 0; r < 4; r++) s += fabsf(acc[i][j][r]);
    atomicAdd(&colpart[wn + j * 16 + (lane & 15)], s);
  }
  __syncthreads();
  if (tid < 128) atomicAdd(&colsum[bn + tid], colpart[tid]);
}

// ---------------- K3 ----------------
__global__ void k_finalize_d(const float* __restrict__ colsum, float* __restrict__ dv) {
  int i = blockIdx.x * blockDim.x + threadIdx.x;
  if (i < IN_F) dv[i] = 1.0f / sqrtf(colsum[i] + 1e-10f);
}

// ---------------- K4: XB = bf16(x * d)  (d folded into x, not P) ----------------
__global__ __launch_bounds__(256) void k_cvt_x(
    const float4* __restrict__ X4, const float4* __restrict__ dv4,
    uint4* __restrict__ XB) {
  size_t t = (size_t)blockIdx.x * 256 + threadIdx.x;  // 8 elems/thread
  int c4 = (int)((2 * t) & (IN_F / 4 - 1));
  float4 a = X4[2 * t], b = X4[2 * t + 1];
  float4 d0 = dv4[c4], d1 = dv4[c4 + 1];
  uint4 o;
  o.x = (uint32_t)f2bf(a.x * d0.x) | ((uint32_t)f2bf(a.y * d0.y) << 16);
  o.y = (uint32_t)f2bf(a.z * d0.z) | ((uint32_t)f2bf(a.w * d0.w) << 16);
  o.z = (uint32_t)f2bf(b.x * d1.x) | ((uint32_t)f2bf(b.y * d1.y) << 16);
  o.w = (uint32_t)f2bf(b.z * d1.z) | ((uint32_t)f2bf(b.w * d1.w) << 16);
  XB[t] = o;
}

// ---------------- K5: out = XB * PB^T + bias ----------------
// 256x128 tile, BK=64, 512 threads (8 waves as 4M x 2N, per-wave 64x64 output).
// Triple-buffered LDS (stage tile t+2 while computing t) -> counted vmcnt(6)
// at tile end (6 gl_lds16/thread/tile outstanding = exactly tile t+2's).
// LDS XOR-swizzle (phys_slot = log_slot ^ (row&7)) applied on the global
// SOURCE address (gl_lds dest stays linear) and on the ds_read address:
// fragment reads hit all 8 16B slots uniformly (8 lanes/slot = b128 floor).
__global__ __launch_bounds__(512, 2) void k_gemm_nt(
    const uint16_t* __restrict__ A,   // [BATCH][IN_F] bf16 (x*d)
    const uint16_t* __restrict__ B,   // [OUT_F][IN_F] bf16 (P)
    const float* __restrict__ bias,
    float* __restrict__ C) {
  __shared__ __align__(16) uint16_t sA[3 * A_TILE_USH];  // 96 KB
  __shared__ __align__(16) uint16_t sB[3 * B_TILE_USH];  // 48 KB

  const int tid  = threadIdx.x;
  const int lane = tid & 63, wid = tid >> 6;

  // XCD-aware swizzle (2048 % 8 == 0 -> simple form is bijective), bn fastest
  const int lin = blockIdx.x;
  const int x   = (lin & 7) * 256 + (lin >> 3);
  const int bn  = (x & 15) * BN;   // out-feature tile (fast -> A-panel reuse)
  const int bm  = (x >> 4) * BM;   // batch tile

  const int wm = (wid >> 1) * 64;  // 4 M-waves
  const int wn = (wid & 1) * 64;   // 2 N-waves

  // ---- staging map: load q covers 16B slot n = q*512 + tid ----
  // row r = n>>3, phys slot s = n&7, logical slot = s ^ (r&7)  (inverse swz)
  const int nA0 = 0 * 512 + tid, nA1 = 1 * 512 + tid, nA2 = 2 * 512 + tid, nA3 = 3 * 512 + tid;
  const int nB0 = 0 * 512 + tid, nB1 = 1 * 512 + tid;
#define SRC_OFF(n) ((size_t)(((n) >> 3)) * IN_F + ((((n) & 7) ^ (((n) >> 3) & 7)) * 8))
  const uint16_t* gA0 = A + (size_t)bm * IN_F + SRC_OFF(nA0);
  const uint16_t* gA1 = A + (size_t)bm * IN_F + SRC_OFF(nA1);
  const uint16_t* gA2 = A + (size_t)bm * IN_F + SRC_OFF(nA2);
  const uint16_t* gA3 = A + (size_t)bm * IN_F + SRC_OFF(nA3);
  const uint16_t* gB0 = B + (size_t)bn * IN_F + SRC_OFF(nB0);
  const uint16_t* gB1 = B + (size_t)bn * IN_F + SRC_OFF(nB1);
#undef SRC_OFF
  // wave-uniform LDS dest offsets (ush); lane scatter is +lane*8 ush by HW
  const int dA0 = (0 * 512 + wid * 64) * 8, dA1 = (1 * 512 + wid * 64) * 8;
  const int dA2 = (2 * 512 + wid * 64) * 8, dA3 = (3 * 512 + wid * 64) * 8;
  const int dB0 = (0 * 512 + wid * 64) * 8, dB1 = (1 * 512 + wid * 64) * 8;

  // ---- fragment read offsets (swizzled): row&7 == lane&7 for all frags ----
  const int rsw0 = (((lane >> 4) + 0) ^ (lane & 7)) * 8;  // k-half 0
  const int rsw1 = (((lane >> 4) + 4) ^ (lane & 7)) * 8;  // k-half 1
  const int raBase = (wm + (lane & 15)) * BK;
  const int rbBase = (wn + (lane & 15)) * BK;

  floatx4 zz = {0.f, 0.f, 0.f, 0.f};
  floatx4 acc[4][4];
#pragma unroll
  for (int i = 0; i < 4; i++)
#pragma unroll
    for (int j = 0; j < 4; j++) acc[i][j] = zz;

  // ---- prologue: stage tiles 0 and 1 ----
  {
    uint16_t* dA = sA;            uint16_t* dB = sB;
    gl_lds16(gA0, dA + dA0); gl_lds16(gA1, dA + dA1);
    gl_lds16(gA2, dA + dA2); gl_lds16(gA3, dA + dA3);
    gl_lds16(gB0, dB + dB0); gl_lds16(gB1, dB + dB1);
    gA0 += BK; gA1 += BK; gA2 += BK; gA3 += BK; gB0 += BK; gB1 += BK;
    dA = sA + A_TILE_USH;         dB = sB + B_TILE_USH;
    gl_lds16(gA0, dA + dA0); gl_lds16(gA1, dA + dA1);
    gl_lds16(gA2, dA + dA2); gl_lds16(gA3, dA + dA3);
    gl_lds16(gB0, dB + dB0); gl_lds16(gB1, dB + dB1);
    gA0 += BK; gA1 += BK; gA2 += BK; gA3 += BK; gB0 += BK; gB1 += BK;
  }
  asm volatile("s_waitcnt vmcnt(6)" ::: "memory");  // tile 0 landed
  __builtin_amdgcn_s_barrier();

  int rb = 0, wb = 2;
  for (int t = 0; t < NKT; t++) {
    const uint16_t* cA = sA + rb * A_TILE_USH;
    const uint16_t* cB = sB + rb * B_TILE_USH;
    uint16_t* dA = sA + wb * A_TILE_USH;
    uint16_t* dB = sB + wb * B_TILE_USH;
    const bool pf = (t + 2 < NKT);

    // ================= phase 0 (k-half 0) =================
    short8 af[4], bf[4];
#pragma unroll
    for (int i = 0; i < 4; i++) af[i] = *(const short8*)&cA[raBase + i * 1024 + rsw0];
#pragma unroll
    for (int j = 0; j < 4; j++) bf[j] = *(const short8*)&cB[rbBase + j * 1024 + rsw0];
    if (pf) {
      gl_lds16(gA0, dA + dA0);
      gl_lds16(gA1, dA + dA1);
      gl_lds16(gB0, dB + dB0);
    }
    __builtin_amdgcn_s_barrier();
    __builtin_amdgcn_s_setprio(1);
#pragma unroll
    for (int i = 0; i < 4; i++)
#pragma unroll
      for (int j = 0; j < 4; j++)
        acc[i][j] = __builtin_amdgcn_mfma_f32_16x16x32_bf16(af[i], bf[j], acc[i][j], 0, 0, 0);
    __builtin_amdgcn_s_setprio(0);
    __builtin_amdgcn_s_barrier();

    // ================= phase 1 (k-half 1) =================
#pragma unroll
    for (int i = 0; i < 4; i++) af[i] = *(const short8*)&cA[raBase + i * 1024 + rsw1];
#pragma unroll
    for (int j = 0; j < 4; j++) bf[j] = *(const short8*)&cB[rbBase + j * 1024 + rsw1];
    if (pf) {
      gl_lds16(gA2, dA + dA2);
      gl_lds16(gA3, dA + dA3);
      gl_lds16(gB1, dB + dB1);
      gA0 += BK; gA1 += BK; gA2 += BK; gA3 += BK; gB0 += BK; gB1 += BK;
    }
    __builtin_amdgcn_s_barrier();
    __builtin_amdgcn_s_setprio(1);
#pragma unroll
    for (int i = 0; i < 4; i++)
#pragma unroll
      for (int j = 0; j < 4; j++)
        acc[i][j] = __builtin_amdgcn_mfma_f32_16x16x32_bf16(af[i], bf[j], acc[i][j], 0, 0, 0);
    __builtin_amdgcn_s_setprio(0);
    // tile-end wait: tile t+1 must be resident before next phase-0 ds_reads.
    // Steady state: exactly tile t+2's 6 loads are newer -> counted vmcnt(6).
    if (t + 2 < NKT) {
      asm volatile("s_waitcnt vmcnt(6)" ::: "memory");
    } else if (t + 1 < NKT) {
      asm volatile("s_waitcnt vmcnt(0)" ::: "memory");
    }
    __builtin_amdgcn_s_barrier();

    rb = (rb == 2) ? 0 : rb + 1;
    wb = (wb == 2) ? 0 : wb + 1;
  }

  // ---- epilogue: C/D layout col = lane&15, row = (lane>>4)*4 + r ----
#pragma unroll
  for (int j = 0; j < 4; j++) {
    const int col = bn + wn + j * 16 + (lane & 15);
    const float bv = bias[col];
#pragma unroll
    for (int i = 0; i < 4; i++) {
      const int row0 = bm + wm + i * 16 + (lane >> 4) * 4;
#pragma unroll
      for (int r = 0; r < 4; r++)
        C[(size_t)(row0 + r) * OUT_F + col] = acc[i][j][r] + bv;
    }
  }
}

// ================= fp32 fallback (only if ws too small) =================
__global__ __launch_bounds__(256) void fb_gram(const float* __restrict__ P,
                                               float* __restrict__ colsum) {
  __shared__ float red[256];
  const int j = blockIdx.x;
  float s = 0.f;
  for (int i = threadIdx.x; i < IN_F; i += 256) {
    float dot = 0.f;
    for (int k = 0; k < OUT_F; k++)
      dot = fmaf(P[(size_t)k * IN_F + i], P[(size_t)k * IN_F + j], dot);
    s += fabsf(dot);
  }
  red[threadIdx.x] = s;
  __syncthreads();
  for (int st = 128; st > 0; st >>= 1) {
    if (threadIdx.x < st) red[threadIdx.x] += red[threadIdx.x + st];
    __syncthreads();
  }
  if (threadIdx.x == 0) colsum[j] = red[0];
}

__global__ __launch_bounds__(256) void fb_gemm(
    const float* __restrict__ X, const float* __restrict__ P,
    const float* __restrict__ dv, const float* __restrict__ bias,
    float* __restrict__ out) {
  __shared__ __align__(16) float xs[64][20];
  __shared__ __align__(16) float ps[64][20];
  const int bm = blockIdx.x * 64, bn = blockIdx.y * 64;
  const int tx = threadIdx.x & 15, ty = threadIdx.x >> 4;
  float acc[4][4] = {};
  const int r = threadIdx.x >> 2, kc = (threadIdx.x & 3) * 4;
  for (int k0 = 0; k0 < IN_F; k0 += 16) {
    float4 xv = *(const float4*)&X[(size_t)(bm + r) * IN_F + k0 + kc];
    float4 pv = *(const float4*)&P[(size_t)(bn + r) * IN_F + k0 + kc];
    float4 dd = *(const float4*)&dv[k0 + kc];
    float4 pw; pw.x = pv.x * dd.x; pw.y = pv.y * dd.y; pw.z = pv.z * dd.z; pw.w = pv.w * dd.w;
    *(float4*)&xs[r][kc] = xv;
    *(float4*)&ps[r][kc] = pw;
    __syncthreads();
#pragma unroll
    for (int kk = 0; kk < 16; kk++) {
      float a0[4], b0[4];
#pragma unroll
      for (int i = 0; i < 4; i++) a0[i] = xs[ty * 4 + i][kk];
#pragma unroll
      for (int jj = 0; jj < 4; jj++) b0[jj] = ps[tx * 4 + jj][kk];
#pragma unroll
      for (int i = 0; i < 4; i++)
#pragma unroll
        for (int jj = 0; jj < 4; jj++) acc[i][jj] = fmaf(a0[i], b0[jj], acc[i][jj]);
    }
    __syncthreads();
  }
#pragma unroll
  for (int i = 0; i < 4; i++)
#pragma unroll
    for (int jj = 0; jj < 4; jj++) {
      int row = bm + ty * 4 + i, col = bn + tx * 4 + jj;
      out[(size_t)row * OUT_F + col] = acc[i][jj] + bias[col];
    }
}

extern "C" void kernel_launch(void* const* d_in, const int* in_sizes, int n_in,
                              void* d_out, int out_size, void* d_ws, size_t ws_size,
                              hipStream_t stream) {
  const float* x    = (const float*)d_in[0];
  const float* P    = (const float*)d_in[1];
  const float* bias = (const float*)d_in[2];
  float* out = (float*)d_out;
  char* ws = (char*)d_ws;

  const size_t SZ_PT = (size_t)IN_F * OUT_F * 2;   // 8 MB
  const size_t SZ_PB = (size_t)IN_F * OUT_F * 2;   // 8 MB
  const size_t SZ_XB = (size_t)BATCH * IN_F * 2;   // 128 MB
  const size_t need  = SZ_PT + SZ_PB + SZ_XB + 2 * IN_F * sizeof(float) + 256;

  if (ws_size >= need) {
    uint16_t* PT = (uint16_t*)ws;
    uint16_t* PB = (uint16_t*)(ws + SZ_PT);
    uint16_t* XB = (uint16_t*)(ws + SZ_PT + SZ_PB);
    float* colsum = (float*)(ws + SZ_PT + SZ_PB + SZ_XB);
    float* dv = colsum + IN_F;

    hipMemsetAsync(colsum, 0, IN_F * sizeof(float), stream);
    k_prep<<<dim3(64, 64), 256, 0, stream>>>(P, PT, PB);
    k_gram_colsum<<<dim3(16, 16), 256, 0, stream>>>(PT, colsum);
    k_finalize_d<<<8, 256, 0, stream>>>(colsum, dv);
    k_cvt_x<<<(int)(((size_t)BATCH * IN_F / 8) / 256), 256, 0, stream>>>(
        (const float4*)x, (const float4*)dv, (uint4*)XB);
    k_gemm_nt<<<(BATCH / BM) * (OUT_F / BN), 512, 0, stream>>>(XB, PB, bias, out);
  } else {
    float* colsum = (float*)ws;
    float* dv = colsum + IN_F;
    fb_gram<<<IN_F, 256, 0, stream>>>(P, colsum);
    k_finalize_d<<<8, 256, 0, stream>>>(colsum, dv);
    fb_gemm<<<dim3(BATCH / 64, OUT_F / 64), 256, 0, stream>>>(x, P, dv, bias, out);
  }
}

// Round 3
// 819.216 us; speedup vs baseline: 1.0425x; 1.0425x over previous
//
#include <hip/hip_runtime.h>
#include <hip/hip_bf16.h>
#include <stdint.h>

#define IN_F  2048
#define OUT_F 2048
#define BATCH 32768

typedef __attribute__((ext_vector_type(8))) short  short8;   // 8 x bf16 (4 VGPRs)
typedef __attribute__((ext_vector_type(4))) float  floatx4;  // MFMA C/D

// ---- 128^2 pipeline constants (k_gram_colsum) ----
static constexpr int LDT = 32;
static constexpr int TILE_USH = 128 * LDT;  // 4096 ushorts = 8 KB per tile

// ---- 256x128 counted-vmcnt GEMM constants ----
#define BM 256
#define BN 128
#define BK 64
#define NKT (IN_F / BK)            // 32 K-tiles
#define A_TILE_USH (BM * BK)       // 16384 ush = 32 KB
#define B_TILE_USH (BN * BK)       // 8192 ush  = 16 KB

__device__ __forceinline__ uint16_t f2bf(float f) {
  union { float f; uint32_t u; } v; v.f = f;
  uint32_t r = v.u + 0x7FFFu + ((v.u >> 16) & 1u);  // RNE
  return (uint16_t)(r >> 16);
}

// 16B-wide async global->LDS. LDS dest is wave-uniform; HW scatters lane l at
// dest + l*16B. Global src is per-lane (enables source-side swizzle).
__device__ __forceinline__ void gl_lds16(const uint16_t* g, uint16_t* l) {
  __builtin_amdgcn_global_load_lds(
      (const __attribute__((address_space(1))) unsigned int*)(g),
      (__attribute__((address_space(3))) unsigned int*)(l), 16, 0, 0);
}

// ===================== m97-structure pipeline (k_gram only) =====================
__device__ __forceinline__ void gemm128_pipeline(
    const uint16_t* __restrict__ A, const uint16_t* __restrict__ B,
    int bm, int bn, int K, uint16_t* sA, uint16_t* sB,
    floatx4 (&acc)[4][4]) {
  const int tid  = threadIdx.x;
  const int wave = tid >> 6, lane = tid & 63;
  const int wm = (wave >> 1) * 64, wn = (wave & 1) * 64;

  const int r0   = wave * 32 + (lane >> 2);
  const int scol = (lane & 3) * 8;
  const uint16_t* gA = A + (size_t)(bm + r0) * K + scol;
  const uint16_t* gB = B + (size_t)(bn + r0) * K + scol;
  const size_t rowK16 = (size_t)16 * K;

  const int ch0 = wave * 2 * (16 * LDT);
  const int ch1 = ch0 + 16 * LDT;

  const int ra = (wm + (lane & 15)) * LDT + (lane >> 4) * 8;
  const int rb = (wn + (lane & 15)) * LDT + (lane >> 4) * 8;

  gl_lds16(gA,          sA + ch0);
  gl_lds16(gA + rowK16, sA + ch1);
  gl_lds16(gB,          sB + ch0);
  gl_lds16(gB + rowK16, sB + ch1);
  gA += 32; gB += 32;
  __syncthreads();

  const int NK = K / 32;
  int p = 0;
  for (int k = 0; k < NK; k++, p ^= 1) {
    if (k + 1 < NK) {
      const int q = (p ^ 1) * TILE_USH;
      gl_lds16(gA,          sA + q + ch0);
      gl_lds16(gA + rowK16, sA + q + ch1);
      gl_lds16(gB,          sB + q + ch0);
      gl_lds16(gB + rowK16, sB + q + ch1);
      gA += 32; gB += 32;
    }
    const uint16_t* cA = sA + p * TILE_USH;
    const uint16_t* cB = sB + p * TILE_USH;
    short8 af[4], bf[4];
#pragma unroll
    for (int i = 0; i < 4; i++) {
      af[i] = *(const short8*)&cA[ra + i * 16 * LDT];
      bf[i] = *(const short8*)&cB[rb + i * 16 * LDT];
    }
#pragma unroll
    for (int i = 0; i < 4; i++)
#pragma unroll
      for (int j = 0; j < 4; j++)
        acc[i][j] = __builtin_amdgcn_mfma_f32_16x16x32_bf16(af[i], bf[j], acc[i][j], 0, 0, 0);
    __syncthreads();
  }
}

// ---------------- K1: P -> PT (bf16 transposed) and PB (bf16 straight) ----------------
__global__ __launch_bounds__(256) void k_prep(
    const float* __restrict__ P, uint16_t* __restrict__ PT,
    uint16_t* __restrict__ PB) {
  __shared__ float tile[32][33];
  const int bx = blockIdx.x * 32;  // i (IN)
  const int by = blockIdx.y * 32;  // k (OUT)
  const int tx = threadIdx.x & 31;
  const int ty = threadIdx.x >> 5;  // 0..7
#pragma unroll
  for (int i = 0; i < 32; i += 8) {
    float v = P[(size_t)(by + ty + i) * IN_F + bx + tx];
    tile[ty + i][tx] = v;
    PB[(size_t)(by + ty + i) * IN_F + bx + tx] = f2bf(v);
  }
  __syncthreads();
#pragma unroll
  for (int i = 0; i < 32; i += 8)
    PT[(size_t)(bx + ty + i) * IN_F + by + tx] = f2bf(tile[tx][ty + i]);
}

// ------- K2: colsum[j] += sum_i |sum_k PT[i,k] PT[j,k]| -------
__global__ __launch_bounds__(256) void k_gram_colsum(
    const uint16_t* __restrict__ PT, float* __restrict__ colsum) {
  __shared__ __align__(16) uint16_t sA[2 * TILE_USH];
  __shared__ __align__(16) uint16_t sB[2 * TILE_USH];
  __shared__ float colpart[128];

  const int tid = threadIdx.x;
  const int wave = tid >> 6, lane = tid & 63;
  const int bm = blockIdx.x * 128, bn = blockIdx.y * 128;
  const int wn = (wave & 1) * 64;

  floatx4 z = {0.f, 0.f, 0.f, 0.f};
  floatx4 acc[4][4];
#pragma unroll
  for (int i = 0; i < 4; i++)
#pragma unroll
    for (int j = 0; j < 4; j++) acc[i][j] = z;

  gemm128_pipeline(PT, PT, bm, bn, OUT_F, sA, sB, acc);

  if (tid < 128) colpart[tid] = 0.f;
  __syncthreads();
#pragma unroll
  for (int j = 0; j < 4; j++) {
    float s = 0.f;
#pragma unroll
    for (int i = 0; i < 4; i++)
#pragma unroll
      for (int r = 0; r < 4; r++) s += fabsf(acc[i][j][r]);
    atomicAdd(&colpart[wn + j * 16 + (lane & 15)], s);
  }
  __syncthreads();
  if (tid < 128) atomicAdd(&colsum[bn + tid], colpart[tid]);
}

// ---------------- K3 ----------------
__global__ void k_finalize_d(const float* __restrict__ colsum, float* __restrict__ dv) {
  int i = blockIdx.x * blockDim.x + threadIdx.x;
  if (i < IN_F) dv[i] = 1.0f / sqrtf(colsum[i] + 1e-10f);
}

// ---------------- K4: XB = bf16(x * d)  (d folded into x, not P) ----------------
__global__ __launch_bounds__(256) void k_cvt_x(
    const float4* __restrict__ X4, const float4* __restrict__ dv4,
    uint4* __restrict__ XB) {
  size_t t = (size_t)blockIdx.x * 256 + threadIdx.x;  // 8 elems/thread
  int c4 = (int)((2 * t) & (IN_F / 4 - 1));
  float4 a = X4[2 * t], b = X4[2 * t + 1];
  float4 d0 = dv4[c4], d1 = dv4[c4 + 1];
  uint4 o;
  o.x = (uint32_t)f2bf(a.x * d0.x) | ((uint32_t)f2bf(a.y * d0.y) << 16);
  o.y = (uint32_t)f2bf(a.z * d0.z) | ((uint32_t)f2bf(a.w * d0.w) << 16);
  o.z = (uint32_t)f2bf(b.x * d1.x) | ((uint32_t)f2bf(b.y * d1.y) << 16);
  o.w = (uint32_t)f2bf(b.z * d1.z) | ((uint32_t)f2bf(b.w * d1.w) << 16);
  XB[t] = o;
}

// ---------------- K5: out = XB * PB^T + bias ----------------
// 256x128 tile, BK=64, 512 threads (8 waves, 4M x 2N, 64x64 out per wave).
// Triple-buffered LDS, ONE barrier per K-tile (after counted vmcnt(6)) —
// waves skew freely within a tile so one wave's ds_reads overlap another's
// MFMAs (m114 co-scheduling). Loop unrolled x3 so every LDS buffer index is a
// compile-time constant (no runtime rb/wb: gives the legalizer provable
// disjointness between gl_lds writes and ds_reads, and immediate offsets).
// LDS XOR-swizzle: phys 16B-slot = log slot ^ (row&7), applied on the global
// SOURCE address (gl_lds dest linear) and on the ds_read address -> 0 bank
// conflicts (verified R2).
__global__ __launch_bounds__(512, 2) void k_gemm_nt(
    const uint16_t* __restrict__ A,   // [BATCH][IN_F] bf16 (x*d)
    const uint16_t* __restrict__ B,   // [OUT_F][IN_F] bf16 (P)
    const float* __restrict__ bias,
    float* __restrict__ C) {
  __shared__ __align__(16) uint16_t sA[3 * A_TILE_USH];  // 96 KB
  __shared__ __align__(16) uint16_t sB[3 * B_TILE_USH];  // 48 KB

  const int tid  = threadIdx.x;
  const int lane = tid & 63, wid = tid >> 6;

  // XCD-aware swizzle (2048 blocks, %8==0 -> bijective), bn fastest
  const int lin = blockIdx.x;
  const int x   = (lin & 7) * 256 + (lin >> 3);
  const int bn  = (x & 15) * BN;   // out-feature tile (fast -> A-panel reuse)
  const int bm  = (x >> 4) * BM;   // batch tile

  const int wm = (wid >> 1) * 64;  // 4 M-waves
  const int wn = (wid & 1) * 64;   // 2 N-waves

  // ---- staging map: load q covers 16B slot n = q*512 + tid ----
  // row r = n>>3, phys slot s = n&7, logical slot = s ^ (r&7)  (inverse swz)
  const int nA0 = 0 * 512 + tid, nA1 = 1 * 512 + tid, nA2 = 2 * 512 + tid, nA3 = 3 * 512 + tid;
  const int nB0 = 0 * 512 + tid, nB1 = 1 * 512 + tid;
#define SRC_OFF(n) ((size_t)(((n) >> 3)) * IN_F + ((((n) & 7) ^ (((n) >> 3) & 7)) * 8))
  const uint16_t* gA0 = A + (size_t)bm * IN_F + SRC_OFF(nA0);
  const uint16_t* gA1 = A + (size_t)bm * IN_F + SRC_OFF(nA1);
  const uint16_t* gA2 = A + (size_t)bm * IN_F + SRC_OFF(nA2);
  const uint16_t* gA3 = A + (size_t)bm * IN_F + SRC_OFF(nA3);
  const uint16_t* gB0 = B + (size_t)bn * IN_F + SRC_OFF(nB0);
  const uint16_t* gB1 = B + (size_t)bn * IN_F + SRC_OFF(nB1);
#undef SRC_OFF
  // wave-uniform LDS dest offsets (ush); lane scatter is +lane*8 ush by HW
  const int dA0 = (0 * 512 + wid * 64) * 8, dA1 = (1 * 512 + wid * 64) * 8;
  const int dA2 = (2 * 512 + wid * 64) * 8, dA3 = (3 * 512 + wid * 64) * 8;
  const int dB0 = (0 * 512 + wid * 64) * 8, dB1 = (1 * 512 + wid * 64) * 8;

  // ---- fragment read offsets (swizzled) ----
  const int rsw0 = (((lane >> 4) + 0) ^ (lane & 7)) * 8;  // k-half 0
  const int rsw1 = (((lane >> 4) + 4) ^ (lane & 7)) * 8;  // k-half 1
  const int raBase = (wm + (lane & 15)) * BK;
  const int rbBase = (wn + (lane & 15)) * BK;

  floatx4 zz = {0.f, 0.f, 0.f, 0.f};
  floatx4 acc[4][4];
#pragma unroll
  for (int i = 0; i < 4; i++)
#pragma unroll
    for (int j = 0; j < 4; j++) acc[i][j] = zz;

  // ---- prologue: stage tiles 0 (buf0) and 1 (buf1) ----
  gl_lds16(gA0, sA + 0 * A_TILE_USH + dA0); gl_lds16(gA1, sA + 0 * A_TILE_USH + dA1);
  gl_lds16(gA2, sA + 0 * A_TILE_USH + dA2); gl_lds16(gA3, sA + 0 * A_TILE_USH + dA3);
  gl_lds16(gB0, sB + 0 * B_TILE_USH + dB0); gl_lds16(gB1, sB + 0 * B_TILE_USH + dB1);
  gA0 += BK; gA1 += BK; gA2 += BK; gA3 += BK; gB0 += BK; gB1 += BK;
  gl_lds16(gA0, sA + 1 * A_TILE_USH + dA0); gl_lds16(gA1, sA + 1 * A_TILE_USH + dA1);
  gl_lds16(gA2, sA + 1 * A_TILE_USH + dA2); gl_lds16(gA3, sA + 1 * A_TILE_USH + dA3);
  gl_lds16(gB0, sB + 1 * B_TILE_USH + dB0); gl_lds16(gB1, sB + 1 * B_TILE_USH + dB1);
  gA0 += BK; gA1 += BK; gA2 += BK; gA3 += BK; gB0 += BK; gB1 += BK;
  asm volatile("s_waitcnt vmcnt(6)" ::: "memory");  // tile 0 landed
  __builtin_amdgcn_s_barrier();

  // TILE body: prefetch (optional) -> 16 ds_reads -> 32 MFMAs -> wait+barrier.
  // WAITN: 6 = steady counted wait, 0 = drain (tail), -1 = none (last tile).
#define TILE(RB, WB, PF, WAITN)                                               \
  do {                                                                        \
    const uint16_t* cA = sA + (RB) * A_TILE_USH;                              \
    const uint16_t* cB = sB + (RB) * B_TILE_USH;                              \
    if (PF) {                                                                 \
      uint16_t* dA = sA + (WB) * A_TILE_USH;                                  \
      uint16_t* dB = sB + (WB) * B_TILE_USH;                                  \
      gl_lds16(gA0, dA + dA0); gl_lds16(gA1, dA + dA1);                       \
      gl_lds16(gA2, dA + dA2); gl_lds16(gA3, dA + dA3);                       \
      gl_lds16(gB0, dB + dB0); gl_lds16(gB1, dB + dB1);                       \
      gA0 += BK; gA1 += BK; gA2 += BK; gA3 += BK; gB0 += BK; gB1 += BK;       \
    }                                                                         \
    short8 af0[4], bf0[4], af1[4], bf1[4];                                    \
    _Pragma("unroll") for (int i = 0; i < 4; i++) {                           \
      af0[i] = *(const short8*)&cA[raBase + i * 1024 + rsw0];                 \
      af1[i] = *(const short8*)&cA[raBase + i * 1024 + rsw1];                 \
    }                                                                         \
    _Pragma("unroll") for (int j = 0; j < 4; j++) {                           \
      bf0[j] = *(const short8*)&cB[rbBase + j * 1024 + rsw0];                 \
      bf1[j] = *(const short8*)&cB[rbBase + j * 1024 + rsw1];                 \
    }                                                                         \
    __builtin_amdgcn_s_setprio(1);                                            \
    _Pragma("unroll") for (int i = 0; i < 4; i++)                             \
      _Pragma("unroll") for (int j = 0; j < 4; j++)                           \
        acc[i][j] = __builtin_amdgcn_mfma_f32_16x16x32_bf16(af0[i], bf0[j], acc[i][j], 0, 0, 0); \
    _Pragma("unroll") for (int i = 0; i < 4; i++)                             \
      _Pragma("unroll") for (int j = 0; j < 4; j++)                           \
        acc[i][j] = __builtin_amdgcn_mfma_f32_16x16x32_bf16(af1[i], bf1[j], acc[i][j], 0, 0, 0); \
    __builtin_amdgcn_s_setprio(0);                                            \
    if ((WAITN) == 6) asm volatile("s_waitcnt vmcnt(6)" ::: "memory");        \
    if ((WAITN) == 0) asm volatile("s_waitcnt vmcnt(0)" ::: "memory");        \
    if ((WAITN) >= 0) __builtin_amdgcn_s_barrier();                           \
  } while (0)

  // t = 0..29: uniform steady state (every tile prefetches t+2 <= 31)
  for (int tt = 0; tt < 30; tt += 3) {
    TILE(0, 2, true, 6);
    TILE(1, 0, true, 6);
    TILE(2, 1, true, 6);
  }
  // t = 30: no prefetch; drain tile 31's loads
  TILE(0, 0, false, 0);
  // t = 31: last tile, no wait/barrier
  TILE(1, 0, false, -1);
#undef TILE

  // ---- epilogue: C/D layout col = lane&15, row = (lane>>4)*4 + r ----
#pragma unroll
  for (int j = 0; j < 4; j++) {
    const int col = bn + wn + j * 16 + (lane & 15);
    const float bv = bias[col];
#pragma unroll
    for (int i = 0; i < 4; i++) {
      const int row0 = bm + wm + i * 16 + (lane >> 4) * 4;
#pragma unroll
      for (int r = 0; r < 4; r++)
        C[(size_t)(row0 + r) * OUT_F + col] = acc[i][j][r] + bv;
    }
  }
}

// ================= fp32 fallback (only if ws too small) =================
__global__ __launch_bounds__(256) void fb_gram(const float* __restrict__ P,
                                               float* __restrict__ colsum) {
  __shared__ float red[256];
  const int j = blockIdx.x;
  float s = 0.f;
  for (int i = threadIdx.x; i < IN_F; i += 256) {
    float dot = 0.f;
    for (int k = 0; k < OUT_F; k++)
      dot = fmaf(P[(size_t)k * IN_F + i], P[(size_t)k * IN_F + j], dot);
    s += fabsf(dot);
  }
  red[threadIdx.x] = s;
  __syncthreads();
  for (int st = 128; st > 0; st >>= 1) {
    if (threadIdx.x < st) red[threadIdx.x] += red[threadIdx.x + st];
    __syncthreads();
  }
  if (threadIdx.x == 0) colsum[j] = red[0];
}

__global__ __launch_bounds__(256) void fb_gemm(
    const float* __restrict__ X, const float* __restrict__ P,
    const float* __restrict__ dv, const float* __restrict__ bias,
    float* __restrict__ out) {
  __shared__ __align__(16) float xs[64][20];
  __shared__ __align__(16) float ps[64][20];
  const int bm = blockIdx.x * 64, bn = blockIdx.y * 64;
  const int tx = threadIdx.x & 15, ty = threadIdx.x >> 4;
  float acc[4][4] = {};
  const int r = threadIdx.x >> 2, kc = (threadIdx.x & 3) * 4;
  for (int k0 = 0; k0 < IN_F; k0 += 16) {
    float4 xv = *(const float4*)&X[(size_t)(bm + r) * IN_F + k0 + kc];
    float4 pv = *(const float4*)&P[(size_t)(bn + r) * IN_F + k0 + kc];
    float4 dd = *(const float4*)&dv[k0 + kc];
    float4 pw; pw.x = pv.x * dd.x; pw.y = pv.y * dd.y; pw.z = pv.z * dd.z; pw.w = pv.w * dd.w;
    *(float4*)&xs[r][kc] = xv;
    *(float4*)&ps[r][kc] = pw;
    __syncthreads();
#pragma unroll
    for (int kk = 0; kk < 16; kk++) {
      float a0[4], b0[4];
#pragma unroll
      for (int i = 0; i < 4; i++) a0[i] = xs[ty * 4 + i][kk];
#pragma unroll
      for (int jj = 0; jj < 4; jj++) b0[jj] = ps[tx * 4 + jj][kk];
#pragma unroll
      for (int i = 0; i < 4; i++)
#pragma unroll
        for (int jj = 0; jj < 4; jj++) acc[i][jj] = fmaf(a0[i], b0[jj], acc[i][jj]);
    }
    __syncthreads();
  }
#pragma unroll
  for (int i = 0; i < 4; i++)
#pragma unroll
    for (int jj = 0; jj < 4; jj++) {
      int row = bm + ty * 4 + i, col = bn + tx * 4 + jj;
      out[(size_t)row * OUT_F + col] = acc[i][jj] + bias[col];
    }
}

extern "C" void kernel_launch(void* const* d_in, const int* in_sizes, int n_in,
                              void* d_out, int out_size, void* d_ws, size_t ws_size,
                              hipStream_t stream) {
  const float* x    = (const float*)d_in[0];
  const float* P    = (const float*)d_in[1];
  const float* bias = (const float*)d_in[2];
  float* out = (float*)d_out;
  char* ws = (char*)d_ws;

  const size_t SZ_PT = (size_t)IN_F * OUT_F * 2;   // 8 MB
  const size_t SZ_PB = (size_t)IN_F * OUT_F * 2;   // 8 MB
  const size_t SZ_XB = (size_t)BATCH * IN_F * 2;   // 128 MB
  const size_t need  = SZ_PT + SZ_PB + SZ_XB + 2 * IN_F * sizeof(float) + 256;

  if (ws_size >= need) {
    uint16_t* PT = (uint16_t*)ws;
    uint16_t* PB = (uint16_t*)(ws + SZ_PT);
    uint16_t* XB = (uint16_t*)(ws + SZ_PT + SZ_PB);
    float* colsum = (float*)(ws + SZ_PT + SZ_PB + SZ_XB);
    float* dv = colsum + IN_F;

    hipMemsetAsync(colsum, 0, IN_F * sizeof(float), stream);
    k_prep<<<dim3(64, 64), 256, 0, stream>>>(P, PT, PB);
    k_gram_colsum<<<dim3(16, 16), 256, 0, stream>>>(PT, colsum);
    k_finalize_d<<<8, 256, 0, stream>>>(colsum, dv);
    k_cvt_x<<<(int)(((size_t)BATCH * IN_F / 8) / 256), 256, 0, stream>>>(
        (const float4*)x, (const float4*)dv, (uint4*)XB);
    k_gemm_nt<<<(BATCH / BM) * (OUT_F / BN), 512, 0, stream>>>(XB, PB, bias, out);
  } else {
    float* colsum = (float*)ws;
    float* dv = colsum + IN_F;
    fb_gram<<<IN_F, 256, 0, stream>>>(P, colsum);
    k_finalize_d<<<8, 256, 0, stream>>>(colsum, dv);
    fb_gemm<<<dim3(BATCH / 64, OUT_F / 64), 256, 0, stream>>>(x, P, dv, bias, out);
  }
}